// Round 3
// baseline (360.769 us; speedup 1.0000x reference)
//
#include <hip/hip_runtime.h>
#include <math.h>

// ArcFace head, B=131072, D=512, C=2. Memory-bound (256 MB feat stream).
// v3: register double-buffered pipeline — prefetch row k+1's float4s before
// consuming row k, so next loads stay in flight (vmcnt(4)) across the
// dot-product + 5-stage shfl butterfly instead of draining to vmcnt(0).
// Discriminating experiment: neutral => kernel is at the 257 MB / 6.3 TB/s
// memory floor and dur_us is harness-dominated.

#define D_DIM 512

__device__ __forceinline__ float dot4(const float4& a, const float4& b) {
    return a.x * b.x + a.y * b.y + a.z * b.z + a.w * b.w;
}

__device__ __forceinline__ float4 scale4(const float4& a, float s) {
    return make_float4(a.x * s, a.y * s, a.z * s, a.w * s);
}

__global__ __launch_bounds__(256, 4) void arcface_kernel(
    const float* __restrict__ feat,
    const float* __restrict__ W,
    const int* __restrict__ label,
    float* __restrict__ out,
    int n_rows)
{
    const float EPS   = 1e-7f;
    const float COS_M = 0.87758256189037271612f;  // cos(0.5)
    const float SIN_M = 0.47942553860420300027f;  // sin(0.5)
    const float S     = 64.0f;

    const int tid  = threadIdx.x;
    const int wave = tid >> 6;
    const int lane = tid & 63;
    const int l32  = lane & 31;

    // ---- W fragments (16 elems/lane/row), norms folded in ----
    const float4* W0v = (const float4*)W;
    const float4* W1v = (const float4*)(W + D_DIM);
    float4 w0[4], w1[4];
    #pragma unroll
    for (int k = 0; k < 4; k++) {
        w0[k] = W0v[l32 + 32 * k];
        w1[k] = W1v[l32 + 32 * k];
    }
    float ss0 = 0.f, ss1 = 0.f;
    #pragma unroll
    for (int k = 0; k < 4; k++) {
        ss0 += dot4(w0[k], w0[k]);
        ss1 += dot4(w1[k], w1[k]);
    }
    #pragma unroll
    for (int m = 16; m >= 1; m >>= 1) {
        ss0 += __shfl_xor(ss0, m);
        ss1 += __shfl_xor(ss1, m);
    }
    const float inv0 = 1.0f / fmaxf(sqrtf(ss0), 1e-12f);
    const float inv1 = 1.0f / fmaxf(sqrtf(ss1), 1e-12f);
    #pragma unroll
    for (int k = 0; k < 4; k++) {
        w0[k] = scale4(w0[k], inv0);
        w1[k] = scale4(w1[k], inv1);
    }

    // ---- one row per half-wave, register-double-buffered pipeline ----
    const int hw  = (blockIdx.x * 4 + wave) * 2 + (lane >> 5);
    const int nhw = gridDim.x * 8;

    float4 cur[4];
    int r = hw;
    if (r < n_rows) {
        const float4* f = (const float4*)(feat + (size_t)r * D_DIM);
        #pragma unroll
        for (int k = 0; k < 4; k++) cur[k] = f[l32 + 32 * k];
    }

    while (r < n_rows) {
        const int  rn  = r + nhw;
        const bool has = (rn < n_rows);

        // Prefetch next row BEFORE consuming cur — these 4 loads remain
        // outstanding (vmcnt(4)) across the dot products and the butterfly.
        float4 nxt[4];
        {
            const float4* f = (const float4*)(feat + (size_t)(has ? rn : r) * D_DIM);
            #pragma unroll
            for (int k = 0; k < 4; k++) nxt[k] = f[l32 + 32 * k];
        }

        float d0 = 0.f, d1 = 0.f, nn = 0.f;
        #pragma unroll
        for (int k = 0; k < 4; k++) {
            d0 += dot4(cur[k], w0[k]);
            d1 += dot4(cur[k], w1[k]);
            nn += dot4(cur[k], cur[k]);
        }
        #pragma unroll
        for (int m = 16; m >= 1; m >>= 1) {
            d0 += __shfl_xor(d0, m);
            d1 += __shfl_xor(d1, m);
            nn += __shfl_xor(nn, m);
        }

        if (l32 == 0) {
            const float invF = 1.0f / fmaxf(sqrtf(nn), 1e-12f);
            float c0 = fminf(fmaxf(d0 * invF, -1.0f + EPS), 1.0f - EPS);
            float c1 = fminf(fmaxf(d1 * invF, -1.0f + EPS), 1.0f - EPS);
            const float m0 = c0 * COS_M - sqrtf(fmaxf(1.0f - c0 * c0, 0.0f)) * SIN_M;
            const float m1 = c1 * COS_M - sqrtf(fmaxf(1.0f - c1 * c1, 0.0f)) * SIN_M;
            const int lb = label[r];
            ((float2*)out)[r] = make_float2(((lb == 0) ? m0 : c0) * S,
                                            ((lb == 1) ? m1 : c1) * S);
        }

        #pragma unroll
        for (int k = 0; k < 4; k++) cur[k] = nxt[k];
        r = rn;
    }
}

extern "C" void kernel_launch(void* const* d_in, const int* in_sizes, int n_in,
                              void* d_out, int out_size, void* d_ws, size_t ws_size,
                              hipStream_t stream) {
    const float* feat  = (const float*)d_in[0];
    const float* W     = (const float*)d_in[1];
    const int*   label = (const int*)d_in[2];
    float*       out   = (float*)d_out;

    const int n_rows = in_sizes[2];  // B = 131072

    // 4096 blocks x 4 waves x 2 halves = 32768 half-waves -> 4 rows each
    // (prologue + 4 pipelined iterations).
    const int blocks = 4096;
    arcface_kernel<<<blocks, 256, 0, stream>>>(feat, W, label, out, n_rows);
}